// Round 7
// baseline (542.935 us; speedup 1.0000x reference)
//
#include <hip/hip_runtime.h>

// MixerBlock: B=8, T=2048, E=1024, H=16, HD=64, DFF=4096, DC=4
// GEMM: 256x256 tile, BK=64, 8 waves (2Mx4N), dbuf 128 KiB LDS.
// r7: faithful m201-style FINE 8-phase schedule. Per K-tile 4 phases:
//   ph q: { ds_read a-frags for mi {2q,2q+1} (4xb128; +8 B-frag reads at ph0,
//           B held in regs all tile) || issue ONE 2-gload stage chunk }
//         -> s_barrier -> lgkmcnt(0)+sched_barrier(0)
//         -> setprio(1) + 16 MFMA + setprio(0)
//         -> counted vmcnt (ph1: 4, ph3: 2; never 0 mid-loop) -> s_barrier
// Stage chunks (2 gloads each) spread 1/phase: ph0 B_h0', ph1 B_h1',
// ph2 A_q02', ph3 A_q13'. FIFO ledger: ph1-end vmcnt(4) forces A_q13(cur)
// [needed ph2]; ph3-end vmcnt(2) forces B+A_q02(t+1) [needed next ph0].
// LDS layout (proven 0-conflict): per matrix [256 rows][8 slots of 8 bf16],
// LDS slot s holds global slot s^(row&7) via pre-swizzled source (rule #21),
// read sl = (ks*4+lk)^(l15&7).

#define TT 2048
#define EE 1024
#define HHD 64
#define MROWS 16384
#define SC_L 64

typedef __bf16 bf16x8 __attribute__((ext_vector_type(8)));
typedef float f32x4 __attribute__((ext_vector_type(4)));
typedef unsigned short u16;
typedef unsigned int u32;

__device__ __forceinline__ u16 f2bf(float f) {
  u32 u = __builtin_bit_cast(u32, f);
  u += 0x7FFFu + ((u >> 16) & 1u);      // round-to-nearest-even
  return (u16)(u >> 16);
}
__device__ __forceinline__ float bf2f(u16 s) {
  u32 u = ((u32)s) << 16;
  return __builtin_bit_cast(float, u);
}
__device__ __forceinline__ float gelu_f(float x) {
  // gelu_tanh(x) = x * sigmoid(2u), u = 0.79788456*x*(1+0.044715 x^2)
  float x2 = x * x;
  float e = -1.5957691216057308f * x * __builtin_fmaf(0.044715f, x2, 1.0f);
  return x * __builtin_amdgcn_rcpf(1.0f + __expf(e));
}
__device__ __forceinline__ void gload_lds16(const void* g, void* l) {
  __builtin_amdgcn_global_load_lds(
      (const __attribute__((address_space(1))) u32*)g,
      (__attribute__((address_space(3))) u32*)l, 16, 0, 0);
}
__device__ __forceinline__ void wg_barrier() {
  asm volatile("" ::: "memory");
  __builtin_amdgcn_s_barrier();
  asm volatile("" ::: "memory");
}

// ---------------- weight transpose + cast: src (R x C) f32 -> dst (C x R) bf16
__global__ __launch_bounds__(256) void transpose_to_bf16(
    const float* __restrict__ src, u16* __restrict__ dst, int R, int C,
    long sbs, long dbs) {
  __shared__ float tile[32][33];
  src += (long)blockIdx.z * sbs;
  dst += (long)blockIdx.z * dbs;
  int c0 = blockIdx.x * 32, r0 = blockIdx.y * 32;
  int tx = threadIdx.x, ty = threadIdx.y;
#pragma unroll
  for (int i = 0; i < 4; i++)
    tile[ty + i * 8][tx] = src[(long)(r0 + ty + i * 8) * C + c0 + tx];
  __syncthreads();
#pragma unroll
  for (int i = 0; i < 4; i++)
    dst[(long)(c0 + ty + i * 8) * R + r0 + tx] = f2bf(tile[tx][ty + i * 8]);
}

// ---------------- LayerNorm over E=1024, one row per block
__global__ __launch_bounds__(256) void ln_to_bf16(
    const float* __restrict__ x, const float* __restrict__ gam,
    const float* __restrict__ bet, u16* __restrict__ y) {
  int row = blockIdx.x;
  int tid = threadIdx.x;
  float4 v = ((const float4*)x)[row * 256 + tid];
  float s = v.x + v.y + v.z + v.w;
  float s2 = v.x * v.x + v.y * v.y + v.z * v.z + v.w * v.w;
#pragma unroll
  for (int off = 1; off < 64; off <<= 1) {
    s += __shfl_xor(s, off);
    s2 += __shfl_xor(s2, off);
  }
  __shared__ float red[8];
  int w = tid >> 6;
  if ((tid & 63) == 0) { red[w] = s; red[4 + w] = s2; }
  __syncthreads();
  s = red[0] + red[1] + red[2] + red[3];
  s2 = red[4] + red[5] + red[6] + red[7];
  float mu = s * (1.0f / 1024.0f);
  float var = s2 * (1.0f / 1024.0f) - mu * mu;
  float rstd = rsqrtf(var + 1e-5f);
  int e0 = tid * 4;
  ushort4 o;
  o.x = f2bf((v.x - mu) * rstd * gam[e0 + 0] + bet[e0 + 0]);
  o.y = f2bf((v.y - mu) * rstd * gam[e0 + 1] + bet[e0 + 1]);
  o.z = f2bf((v.z - mu) * rstd * gam[e0 + 2] + bet[e0 + 2]);
  o.w = f2bf((v.w - mu) * rstd * gam[e0 + 3] + bet[e0 + 3]);
  ((ushort4*)y)[row * 256 + tid] = o;
}

// ---------------- bf16 GEMM, 256x256, BK=64, fine 8-phase counted-vmcnt.
// A: (M x K) bf16 rm. Bt: (N x K) bf16 rm.
// LDS buffer c at c*32768 (u16): A [0,16384), B [16384,32768).
// EPI 0: bf16 = acc+bias ; 1: f32 = acc+bias+res ; 2: bf16 = gelu(acc+bias)
template <int EPI>
__global__ __launch_bounds__(512, 2) void gemm256(
    const u16* __restrict__ A, const u16* __restrict__ Bt,
    const float* __restrict__ bias, const float* __restrict__ res, void* outp,
    int M, int N, int K, int px, int gxp, int byper) {
  __shared__ u16 lds[65536];  // 128 KiB
  const int tid = threadIdx.x;
  const int w = tid >> 6, lane = tid & 63;
  const int wm = w >> 2, wn = w & 3;
  const int l15 = lane & 15, lk = lane >> 4;

  // L2-locality supertile swizzle (bijective; nwg % 8 == 0 for all launches)
  const int gx = (int)gridDim.x;
  const int bid = (int)blockIdx.y * gx + (int)blockIdx.x;
  const int xcd = bid & 7, i = bid >> 3;
  const int xg = xcd % gxp, yg = xcd / gxp;
  const int bx = xg * px + (i % px);
  const int by = yg * byper + (i / px);
  const int m0 = by * 256, n0 = bx * 256;

  // Staging: one gload covers 64 rows (wave w -> rows w*8+[0,8), slot lane&7,
  // source slot pre-swizzled by row&7).
  const int srow = w * 8 + (lane >> 3);
  const int sslot = (lane & 7) ^ (lane >> 3);
  const u16* aS = A + (size_t)(m0 + srow) * K + sslot * 8;
  const u16* bS = Bt + (size_t)(n0 + srow) * K + sslot * 8;

  f32x4 acc[8][4];
  const f32x4 z = {0.f, 0.f, 0.f, 0.f};
#pragma unroll
  for (int mi = 0; mi < 8; mi++)
#pragma unroll
    for (int ni = 0; ni < 4; ni++) acc[mi][ni] = z;

  bf16x8 a[4];       // a-frags of current phase: [mm*2+ks]
  bf16x8 bq[2][4];   // B frags for whole tile: [ks][ni]

  const int sl0 = (lk ^ (l15 & 7)) * 8;        // ks0 slot byte-off (u16 units)
  const int sl1 = ((4 + lk) ^ (l15 & 7)) * 8;  // ks1

#define STAGE_B(C, KT, H) { \
    u16* lb = lds + (C) * 32768 + 16384 + (H) * 8192 + w * 512; \
    gload_lds16(bS + (size_t)((H) * 128) * K + (KT), lb); \
    gload_lds16(bS + (size_t)((H) * 128 + 64) * K + (KT), lb + 4096); }

#define STAGE_A02(C, KT) { \
    u16* lb = lds + (C) * 32768 + w * 512; \
    gload_lds16(aS + (KT), lb); \
    gload_lds16(aS + (size_t)128 * K + (KT), lb + 8192); }

#define STAGE_A13(C, KT) { \
    u16* lb = lds + (C) * 32768 + 4096 + w * 512; \
    gload_lds16(aS + (size_t)64 * K + (KT), lb); \
    gload_lds16(aS + (size_t)192 * K + (KT), lb + 8192); }

  // reads: phase Q reads a-frags for mi in {2Q, 2Q+1}
#define RD_AQ(C, Q) { \
    const u16* base = lds + (C) * 32768 + (wm * 128 + (Q) * 32 + l15) * 64; \
    a[0] = *(const bf16x8*)(base + sl0); \
    a[1] = *(const bf16x8*)(base + sl1); \
    a[2] = *(const bf16x8*)(base + 16 * 64 + sl0); \
    a[3] = *(const bf16x8*)(base + 16 * 64 + sl1); }

#define RD_BALL(C) { \
    const u16* base = lds + (C) * 32768 + 16384 + (wn * 64 + l15) * 64; \
    _Pragma("unroll") \
    for (int ni = 0; ni < 4; ni++) { \
      bq[0][ni] = *(const bf16x8*)(base + ni * 16 * 64 + sl0); \
      bq[1][ni] = *(const bf16x8*)(base + ni * 16 * 64 + sl1); } }

#define BAR_MID() { \
    wg_barrier(); \
    asm volatile("s_waitcnt lgkmcnt(0)" ::: "memory"); \
    __builtin_amdgcn_sched_barrier(0); }

#define MFMAQ(Q) { \
    __builtin_amdgcn_s_setprio(1); \
    _Pragma("unroll") \
    for (int ks = 0; ks < 2; ks++) \
      _Pragma("unroll") \
      for (int mm = 0; mm < 2; mm++) \
        _Pragma("unroll") \
        for (int nn = 0; nn < 4; nn++) \
          acc[(Q) * 2 + mm][nn] = __builtin_amdgcn_mfma_f32_16x16x32_bf16( \
              a[mm * 2 + ks], bq[ks][nn], acc[(Q) * 2 + mm][nn], 0, 0, 0); \
    __builtin_amdgcn_s_setprio(0); }

  const int nt = K >> 6;
  // prologue: stage tile 0 fully into buf 0; force B+A02, leave A13 in flight
  STAGE_B(0, 0, 0);
  STAGE_B(0, 0, 1);
  STAGE_A02(0, 0);
  STAGE_A13(0, 0);
  asm volatile("s_waitcnt vmcnt(2)" ::: "memory");
  wg_barrier();

  int cur = 0;
  for (int t = 0; t < nt; ++t) {
    const int nx = cur ^ 1;
    const int kn = (t + 1) << 6;
    const bool pf = (t + 1 < nt);
    // ph0: B all (8) + A q0 (4) ; stage B_h0'
    RD_BALL(cur);
    RD_AQ(cur, 0);
    if (pf) STAGE_B(nx, kn, 0);
    BAR_MID();
    MFMAQ(0);
    wg_barrier();
    // ph1: A q1 ; stage B_h1'
    RD_AQ(cur, 1);
    if (pf) STAGE_B(nx, kn, 1);
    BAR_MID();
    MFMAQ(1);
    if (pf) {
      asm volatile("s_waitcnt vmcnt(4)" ::: "memory");  // forces A_q13(cur)
    } else {
      asm volatile("s_waitcnt vmcnt(0)" ::: "memory");  // last tile drain
    }
    wg_barrier();
    // ph2: A q2 ; stage A_q02'
    RD_AQ(cur, 2);
    if (pf) STAGE_A02(nx, kn);
    BAR_MID();
    MFMAQ(2);
    wg_barrier();
    // ph3: A q3 ; stage A_q13'
    RD_AQ(cur, 3);
    if (pf) STAGE_A13(nx, kn);
    BAR_MID();
    MFMAQ(3);
    asm volatile("s_waitcnt vmcnt(2)" ::: "memory");  // forces B+A_q02(t+1); no-op on last
    wg_barrier();
    cur = nx;
  }
#undef STAGE_B
#undef STAGE_A02
#undef STAGE_A13
#undef RD_AQ
#undef RD_BALL
#undef BAR_MID
#undef MFMAQ

#pragma unroll
  for (int mi = 0; mi < 8; mi++) {
#pragma unroll
    for (int ni = 0; ni < 4; ni++) {
      int n = n0 + wn * 64 + ni * 16 + l15;       // C/D: col = lane&15
      float bvv = bias[n];
#pragma unroll
      for (int r = 0; r < 4; r++) {
        int m = m0 + wm * 128 + mi * 16 + lk * 4 + r;  // row = (lane>>4)*4 + reg
        size_t idx = (size_t)m * N + n;
        float v = acc[mi][ni][r] + bvv;
        if (EPI == 0) {
          ((u16*)outp)[idx] = f2bf(v);
        } else if (EPI == 1) {
          ((float*)outp)[idx] = v + res[idx];
        } else {
          ((u16*)outp)[idx] = f2bf(gelu_f(v));
        }
      }
    }
  }
}

// ---------------- causal decay mixing as a chunked linear scan.
__global__ __launch_bounds__(64) void scan_carry(
    const u16* __restrict__ p, const float* __restrict__ mix_w,
    const float* __restrict__ decay, float* __restrict__ carry) {
  int blk = blockIdx.x;
  int c = blk & 31, h = (blk >> 5) & 15, b = blk >> 9;
  int f = threadIdx.x;
  float d = fminf(fmaxf(decay[h], 0.9f), 1.0f);
  float r = powf(d, 0.25f);
  size_t base = ((size_t)b * TT + c * SC_L) * EE + h * HHD + f;
  const float* mw = mix_w + h * TT + c * SC_L;
  bool isRow = (h >= 8);
  float S = 0.f;
#pragma unroll 4
  for (int t = 0; t < SC_L; t++) {
    float pv = bf2f(p[base + (size_t)t * EE]);
    float q = isRow ? mw[t] * pv : pv;
    S = r * S + q;
  }
  carry[blk * 64 + f] = S;
}

__global__ __launch_bounds__(64) void scan_apply(
    const u16* __restrict__ p, const float* __restrict__ mix_w,
    const float* __restrict__ mix_b, const float* __restrict__ decay,
    const float* __restrict__ carry, u16* __restrict__ mixed) {
  int blk = blockIdx.x;
  int c = blk & 31, h = (blk >> 5) & 15, b = blk >> 9;
  int f = threadIdx.x;
  float d = fminf(fmaxf(decay[h], 0.9f), 1.0f);
  float r = powf(d, 0.25f);
  float rl = powf(r, (float)SC_L);
  int cb = blk - c;
  float S = 0.f;
  for (int cc = 0; cc < c; cc++) S = rl * S + carry[(cb + cc) * 64 + f];
  size_t base = ((size_t)b * TT + c * SC_L) * EE + h * HHD + f;
  const float* mw = mix_w + h * TT + c * SC_L;
  const float* mb = mix_b + h * TT + c * SC_L;
  bool isRow = (h >= 8);
  for (int t = 0; t < SC_L; t++) {
    float pv = bf2f(p[base + (size_t)t * EE]);
    float q = isRow ? mw[t] * pv : pv;
    S = r * S + q;
    float val = (isRow ? S : mw[t] * S) + mb[t];
    mixed[base + (size_t)t * EE] = f2bf(val);
  }
}

extern "C" void kernel_launch(void* const* d_in, const int* in_sizes, int n_in,
                              void* d_out, int out_size, void* d_ws, size_t ws_size,
                              hipStream_t stream) {
  const float* x = (const float*)d_in[0];
  const float* w_proj = (const float*)d_in[1];
  const float* b_proj = (const float*)d_in[2];
  const float* mix_w = (const float*)d_in[3];
  const float* mix_b = (const float*)d_in[4];
  const float* decay = (const float*)d_in[5];
  const float* out_w = (const float*)d_in[6];
  const float* out_b = (const float*)d_in[7];
  const float* ln1_g = (const float*)d_in[8];
  const float* ln1_b = (const float*)d_in[9];
  const float* ln2_g = (const float*)d_in[10];
  const float* ln2_b = (const float*)d_in[11];
  const float* ff_w1 = (const float*)d_in[12];
  const float* ff_b1 = (const float*)d_in[13];
  const float* ff_w2 = (const float*)d_in[14];
  const float* ff_b2 = (const float*)d_in[15];
  float* out = (float*)d_out;

  // ws layout (MiB): [0,2)Wp [2,4)Wo [4,12)W1 [12,20)W2 [20,52)mixed/g
  //                  [52,180)u (h at 52, p at 84) [180,181)carry
  char* ws = (char*)d_ws;
  const size_t MiB = 1ull << 20;
  u16* wWp = (u16*)(ws + 0 * MiB);
  u16* wWo = (u16*)(ws + 2 * MiB);
  u16* wW1 = (u16*)(ws + 4 * MiB);
  u16* wW2 = (u16*)(ws + 12 * MiB);
  u16* wMix = (u16*)(ws + 20 * MiB);
  u16* wH = (u16*)(ws + 52 * MiB);
  u16* wP = (u16*)(ws + 84 * MiB);
  u16* wU = (u16*)(ws + 52 * MiB);
  float* wCarry = (float*)(ws + 180 * MiB);

  dim3 tb(32, 8);
  transpose_to_bf16<<<dim3(2, 32, 16), tb, 0, stream>>>(w_proj, wWp, 1024, 64,
                                                        65536L, 65536L);
  transpose_to_bf16<<<dim3(32, 32, 1), tb, 0, stream>>>(out_w, wWo, 1024, 1024, 0L, 0L);
  transpose_to_bf16<<<dim3(128, 32, 1), tb, 0, stream>>>(ff_w1, wW1, 1024, 4096, 0L, 0L);
  transpose_to_bf16<<<dim3(32, 128, 1), tb, 0, stream>>>(ff_w2, wW2, 4096, 1024, 0L, 0L);

  ln_to_bf16<<<dim3(MROWS), dim3(256), 0, stream>>>(x, ln1_g, ln1_b, wH);

  // G1: px=4 (B 2MB fully L2/XCD), gxp=1, byper=8
  gemm256<0><<<dim3(4, 64), dim3(512), 0, stream>>>(
      wH, wWp, b_proj, (const float*)nullptr, (void*)wP, MROWS, 1024, 1024,
      4, 1, 8);

  scan_carry<<<dim3(4096), dim3(64), 0, stream>>>(wP, mix_w, decay, wCarry);
  scan_apply<<<dim3(4096), dim3(64), 0, stream>>>(wP, mix_w, mix_b, decay, wCarry, wMix);

  // G2: same shape as G1
  gemm256<1><<<dim3(4, 64), dim3(512), 0, stream>>>(
      wMix, wWo, out_b, x, (void*)out, MROWS, 1024, 1024,
      4, 1, 8);

  ln_to_bf16<<<dim3(MROWS), dim3(256), 0, stream>>>(out, ln2_g, ln2_b, wMix);

  // G3: px=4, gxp=4, byper=32
  gemm256<2><<<dim3(16, 64), dim3(512), 0, stream>>>(
      wMix, wW1, ff_b1, (const float*)nullptr, (void*)wU, MROWS, 4096, 1024,
      4, 4, 32);

  // G4: px=2, gxp=2, byper=16
  gemm256<1><<<dim3(4, 64), dim3(512), 0, stream>>>(
      wU, wW2, ff_b2, out, (void*)out, MROWS, 1024, 4096,
      2, 2, 16);
}